// Round 6
// baseline (1278.666 us; speedup 1.0000x reference)
//
#include <hip/hip_runtime.h>
#include <hip/hip_bf16.h>

#define BB 32
#define TT 120
#define EE 300
#define HH 256
#define VV 32000
#define CC 512
#define GG 49      // 7*7
#define KIN 556    // E+H
#define CF 25088   // C*49

typedef __attribute__((ext_vector_type(8))) short bf16x8;
typedef __attribute__((ext_vector_type(4))) float f32x4;

// ---- packed-bf16 helpers ----
__device__ __forceinline__ float bpair_lo(unsigned int u) { return __uint_as_float(u << 16); }
__device__ __forceinline__ float bpair_hi(unsigned int u) { return __uint_as_float(u & 0xFFFF0000u); }

__device__ __forceinline__ unsigned int packbf(float a, float b) {
    union { __hip_bfloat16 h; unsigned short u; } ua, ub;
    ua.h = __float2bfloat16(a); ub.h = __float2bfloat16(b);
    return (unsigned int)ua.u | ((unsigned int)ub.u << 16);
}
__device__ __forceinline__ unsigned short f2bu(float x) {
    union { __hip_bfloat16 h; unsigned short u; } v; v.h = __float2bfloat16(x); return v.u;
}

#if defined(__has_builtin)
#  if __has_builtin(__builtin_amdgcn_fdot2_f32_bf16)
#    define USE_DOT2 1
#  endif
#endif
#ifndef USE_DOT2
#  define USE_DOT2 0
#endif

#if USE_DOT2
typedef __bf16 bf2_t __attribute__((ext_vector_type(2)));
__device__ __forceinline__ float dot2bf(unsigned int w, unsigned int h, float c) {
    return __builtin_amdgcn_fdot2_f32_bf16(__builtin_bit_cast(bf2_t, w),
                                           __builtin_bit_cast(bf2_t, h), c, false);
}
#else
__device__ __forceinline__ float dot2bf(unsigned int w, unsigned int h, float c) {
    c = fmaf(bpair_lo(w), bpair_lo(h), c);
    c = fmaf(bpair_hi(w), bpair_hi(h), c);
    return c;
}
#endif

// ---------------- mean: features [B,C,49] -> mean_f [B,C], 512 blocks ----------------
__global__ void __launch_bounds__(256) k_mean(const float* __restrict__ features,
                                              float* __restrict__ mean_f) {
    int q = blockIdx.x;   // c-chunk 0..15 (32 c each)
    int b = blockIdx.y;
    __shared__ float lds[32 * GG];
    const float* src = features + (size_t)b * CF + (size_t)q * 32 * GG;
    for (int i = threadIdx.x; i < 32 * GG; i += 256) lds[i] = src[i];
    __syncthreads();
    if (threadIdx.x < 32) {
        const float* p = &lds[threadIdx.x * GG];
        float s = 0.f;
#pragma unroll
        for (int i = 0; i < GG; ++i) s += p[i];
        mean_f[b * CC + q * 32 + threadIdx.x] = s * (1.0f / 49.0f);
    }
}

// ---------------- h0 = mean_f @ W_init.T + b_init -> [B,H] ----------------
__global__ void k_h0(const float* __restrict__ mean_f, const float* __restrict__ W_init,
                     const float* __restrict__ b_init, float* __restrict__ h0) {
    __shared__ float mf[CC];
    int b = blockIdx.x;
    for (int i = threadIdx.x; i < CC; i += 256) mf[i] = mean_f[b * CC + i];
    __syncthreads();
    int h = threadIdx.x;
    const float* w = W_init + (size_t)h * CC;
    float s = 0.f;
    for (int k = 0; k < CC; k += 4) {
        float4 w4 = *(const float4*)(w + k);
        s += mf[k] * w4.x + mf[k + 1] * w4.y + mf[k + 2] * w4.z + mf[k + 3] * w4.w;
    }
    h0[b * HH + h] = s + b_init[h];
}

// ---------------- fc2 stage A: K-split partial GEMM, coalesced W via LDS transpose ----------------
__global__ void __launch_bounds__(256) k_fc2a(const float* __restrict__ features,
                                              const float* __restrict__ W_fc2,
                                              float* __restrict__ part) {
    int kc = blockIdx.x;
    __shared__ float xs[98][BB];          // 12.5 KB
    __shared__ float wtile[16][257];      // 16.4 KB
    for (int idx = threadIdx.x; idx < 98 * BB; idx += 256) {
        int ii = idx >> 5, b = idx & 31;
        int ig = kc * 98 + ii;
        int c = ig & 511, p = ig >> 9;
        xs[ii][b] = features[(size_t)b * CF + c * GG + p];
    }
    int h = threadIdx.x;
    float acc[BB];
#pragma unroll
    for (int b = 0; b < BB; ++b) acc[b] = 0.f;
    for (int cc = 0; cc < 7; ++cc) {
        int cw = (cc < 6) ? 16 : 2;
        __syncthreads();
        for (int idx = threadIdx.x; idx < 256 * cw; idx += 256) {
            int hr = idx / cw, cl = idx - hr * cw;   // cw=16: idx>>4/&15; keep generic
            wtile[cl][hr] = W_fc2[(size_t)hr * CF + kc * 98 + cc * 16 + cl];
        }
        __syncthreads();
        for (int ii = 0; ii < cw; ++ii) {
            float w = wtile[ii][h];
            const float4* xv = (const float4*)&xs[cc * 16 + ii][0];
#pragma unroll
            for (int q = 0; q < 8; ++q) {
                float4 v = xv[q];
                acc[4 * q + 0] += w * v.x;
                acc[4 * q + 1] += w * v.y;
                acc[4 * q + 2] += w * v.z;
                acc[4 * q + 3] += w * v.w;
            }
        }
    }
    float* pp = part + (size_t)kc * (BB * 256) + h;
#pragma unroll
    for (int b = 0; b < BB; ++b) pp[b * 256] = acc[b];
}

// ---------------- fc2 stage B: reduce partials -> feat [B,H] ----------------
__global__ void k_fc2b(const float* __restrict__ part, const float* __restrict__ b_fc2,
                       float* __restrict__ feat) {
    int b = blockIdx.x;
    int h = threadIdx.x;
    float s = b_fc2[h];
    const float* pp = part + b * 256 + h;
#pragma unroll 8
    for (int kc = 0; kc < 256; ++kc) s += pp[(size_t)kc * (BB * 256)];
    feat[b * HH + h] = s;
}

// ---------------- gfeat[b][g] = feat @ W_ih[:,300:].T + b_ih  (time-invariant part) ----------------
__global__ void __launch_bounds__(256) k_gfeat(const float* __restrict__ feat,
                                               const float* __restrict__ W_ih,
                                               const float* __restrict__ b_ih,
                                               float* __restrict__ gfeat) {
    int ch = blockIdx.x;   // 0..3
    int bh = blockIdx.y;   // 0..1
    __shared__ float xf[16][HH + 1];
    for (int i = threadIdx.x; i < 16 * HH; i += 256) {
        int r = i >> 8, c = i & 255;
        xf[r][c] = feat[(bh * 16 + r) * HH + c];
    }
    __syncthreads();
    int bloc = threadIdx.x & 15;
    int jj   = threadIdx.x >> 4;
    int g0   = ch * 192 + jj;
    float acc[12];
#pragma unroll
    for (int i = 0; i < 12; ++i) acc[i] = 0.f;
    for (int k = 0; k < HH; k += 4) {
        float x0 = xf[bloc][k], x1 = xf[bloc][k + 1], x2 = xf[bloc][k + 2], x3 = xf[bloc][k + 3];
#pragma unroll
        for (int i = 0; i < 12; ++i) {
            float4 w4 = *(const float4*)(W_ih + (size_t)(g0 + i * 16) * KIN + EE + k);
            acc[i] += x0 * w4.x + x1 * w4.y + x2 * w4.z + x3 * w4.w;
        }
    }
    float* outp = gfeat + (size_t)(bh * 16 + bloc) * 768;
#pragma unroll
    for (int i = 0; i < 12; ++i) {
        int g = g0 + i * 16;
        outp[g] = acc[i] + b_ih[g];
    }
}

// ---------------- gi[t,b,g] = emb-part + gfeat ----------------
__global__ void __launch_bounds__(256) k_gi(const float* __restrict__ emb,
                                            const float* __restrict__ gfeat,
                                            const float* __restrict__ W_ih,
                                            float* __restrict__ gi) {
    int ch = blockIdx.x;   // 0..3
    int t  = blockIdx.y;   // 0..119
    int bh = blockIdx.z;   // 0..1
    __shared__ float x[16][EE + 1];   // 19.3 KB
    for (int i = threadIdx.x; i < 16 * EE; i += 256) {
        int r = i / EE, c = i - r * EE;
        x[r][c] = emb[(size_t)(bh * 16 + r) * TT * EE + (size_t)t * EE + c];
    }
    __syncthreads();
    int bloc = threadIdx.x & 15;
    int jj   = threadIdx.x >> 4;
    int g0   = ch * 192 + jj;
    float acc[12];
#pragma unroll
    for (int i = 0; i < 12; ++i) acc[i] = 0.f;
    for (int k = 0; k < EE; k += 4) {
        float x0 = x[bloc][k], x1 = x[bloc][k + 1], x2 = x[bloc][k + 2], x3 = x[bloc][k + 3];
#pragma unroll
        for (int i = 0; i < 12; ++i) {
            float4 w4 = *(const float4*)(W_ih + (size_t)(g0 + i * 16) * KIN + k);
            acc[i] += x0 * w4.x + x1 * w4.y + x2 * w4.z + x3 * w4.w;
        }
    }
    int bg = bh * 16 + bloc;
    float* outp = gi + ((size_t)t * BB + bg) * 768;
    const float* gf = gfeat + (size_t)bg * 768;
#pragma unroll
    for (int i = 0; i < 12; ++i) {
        int g = g0 + i * 16;
        outp[g] = acc[i] + gf[g];
    }
}

// ---------------- persistent GRU: 32 blocks x 768 threads, 2 barriers/step ----------------
__global__ void __launch_bounds__(768, 3) k_gru(const float* __restrict__ h0,
                                                const float* __restrict__ gi,
                                                const float* __restrict__ W_hh,
                                                const float* __restrict__ b_hh,
                                                unsigned short* __restrict__ hA) {
    int b  = blockIdx.x;
    int jp = threadIdx.x;
    int j  = jp & 255;
    int g  = jp >> 8;
    __shared__ unsigned int h_pk[128];          // packed bf16 h pairs
    __shared__ float r_sh[256];
    __shared__ float z_sh[256];
    __shared__ unsigned short hAt[40][256];     // 20 KB chunk of h history

    unsigned int wreg[128];
    const float* wrow = W_hh + (size_t)jp * HH;
#pragma unroll
    for (int kk = 0; kk < 128; ++kk) {
        float2 w2 = *(const float2*)(wrow + 2 * kk);
        wreg[kk] = packbf(w2.x, w2.y);
    }
    float bias  = b_hh[jp];
    float hprev = (g == 2) ? h0[b * HH + j] : 0.f;
    if (jp < 128) {
        float2 hp2 = *(const float2*)(h0 + b * HH + 2 * jp);
        h_pk[jp] = packbf(hp2.x, hp2.y);
    }
    __syncthreads();

    const float* gip = gi + (size_t)b * 768 + jp;    // + t*BB*768 per step
    float gx = gip[0];

    for (int tc = 0; tc < 3; ++tc) {
        for (int tl = 0; tl < 40; ++tl) {
            int t = tc * 40 + tl;
            float a0 = 0.f, a1 = 0.f, a2 = 0.f, a3 = 0.f;
#pragma unroll
            for (int kk = 0; kk < 128; kk += 4) {
                uint4 hq = *(const uint4*)&h_pk[kk];
                a0 = dot2bf(wreg[kk + 0], hq.x, a0);
                a1 = dot2bf(wreg[kk + 1], hq.y, a1);
                a2 = dot2bf(wreg[kk + 2], hq.z, a2);
                a3 = dot2bf(wreg[kk + 3], hq.w, a3);
            }
            float a = (a0 + a1) + (a2 + a3);
            if (g == 0)      r_sh[j] = 1.f / (1.f + __expf(-(gx + a + bias)));
            else if (g == 1) z_sh[j] = 1.f / (1.f + __expf(-(gx + a + bias)));
            __syncthreads();                              // A: r,z visible
            if (g == 2) {
                float n  = tanhf(gx + r_sh[j] * (a + bias));
                float z  = z_sh[j];
                float hn = (1.f - z) * n + z * hprev;
                hprev = hn;
                hAt[tl][j] = f2bu(hn);
                float hnb = __shfl_xor(hn, 1);
                if ((j & 1) == 0) h_pk[j >> 1] = packbf(hn, hnb);
            }
            __syncthreads();                              // B: h_pk ready
            if (t + 1 < TT) gx = gip[(size_t)(t + 1) * (BB * 768)];
        }
        // coalesced flush of 40-step chunk (uint = 2 bf16)
        for (int idx = jp; idx < 40 * 128; idx += 768) {
            int tl = idx >> 7, jh = idx & 127;
            unsigned int v = *(const unsigned int*)&hAt[tl][jh * 2];
            *(unsigned int*)&hA[((size_t)b * TT + tc * 40 + tl) * HH + jh * 2] = v;
        }
        __syncthreads();
    }
}

// ---------------- W_fc f32 -> bf16 ----------------
__global__ void k_cvt(const float* __restrict__ src, __hip_bfloat16* __restrict__ dst) {
    size_t i = ((size_t)blockIdx.x * 256 + threadIdx.x) * 4;
    float4 v = *(const float4*)(src + i);
    __hip_bfloat16 o[4];
    o[0] = __float2bfloat16(v.x);
    o[1] = __float2bfloat16(v.y);
    o[2] = __float2bfloat16(v.z);
    o[3] = __float2bfloat16(v.w);
    *(uint2*)(dst + i) = *(uint2*)o;
}

// ---------------- logits: LDS-staged MFMA GEMM, 128x128 tile, BK=64 ----------------
__global__ void __launch_bounds__(256) k_logits(const __hip_bfloat16* __restrict__ hA,
                                                const __hip_bfloat16* __restrict__ wfc,
                                                const float* __restrict__ b_fc,
                                                float* __restrict__ out) {
    __shared__ short As[128][64];
    __shared__ short Bs[128][64];
    char* AsB = (char*)As;
    char* BsB = (char*)Bs;

    int nt = blockIdx.x;
    int mt = blockIdx.y;
    int tid  = threadIdx.x;
    int wave = tid >> 6, lane = tid & 63;
    int wm = wave >> 1, wn = wave & 1;
    int lr = lane & 15;
    int lk = lane >> 4;

    int rs = tid >> 3;
    int cs = tid & 7;
    const short* Ag = (const short*)hA  + (size_t)mt * 128 * HH + (size_t)rs * HH + cs * 8;
    const short* Bg = (const short*)wfc + (size_t)nt * 128 * HH + (size_t)rs * HH + cs * 8;
    int wswz = (cs ^ (rs & 7)) * 16;
    int wofs[4];
#pragma unroll
    for (int p = 0; p < 4; ++p) wofs[p] = (p * 32 + rs) * 128 + wswz;

    f32x4 acc[4][4] = {};

#define LOADT(kt, GA, GB)                                                        \
    do {                                                                         \
        _Pragma("unroll") for (int p = 0; p < 4; ++p)                            \
            GA[p] = *(const bf16x8*)(Ag + (size_t)p * 32 * HH + (kt) * 64);      \
        _Pragma("unroll") for (int p = 0; p < 4; ++p)                            \
            GB[p] = *(const bf16x8*)(Bg + (size_t)p * 32 * HH + (kt) * 64);      \
    } while (0)

#define STORET(GA, GB)                                                           \
    do {                                                                         \
        _Pragma("unroll") for (int p = 0; p < 4; ++p)                            \
            *(bf16x8*)(AsB + wofs[p]) = GA[p];                                   \
        _Pragma("unroll") for (int p = 0; p < 4; ++p)                            \
            *(bf16x8*)(BsB + wofs[p]) = GB[p];                                   \
    } while (0)

#define COMPUTE()                                                                \
    do {                                                                         \
        _Pragma("unroll") for (int kk = 0; kk < 2; ++kk) {                       \
            bf16x8 af[4], bg[4];                                                 \
            _Pragma("unroll") for (int i = 0; i < 4; ++i) {                      \
                int r = wm * 64 + i * 16 + lr;                                   \
                af[i] = *(const bf16x8*)(AsB + r * 128 + (((kk * 4 + lk) ^ (r & 7)) * 16)); \
            }                                                                    \
            _Pragma("unroll") for (int j = 0; j < 4; ++j) {                      \
                int r = wn * 64 + j * 16 + lr;                                   \
                bg[j] = *(const bf16x8*)(BsB + r * 128 + (((kk * 4 + lk) ^ (r & 7)) * 16)); \
            }                                                                    \
            _Pragma("unroll") for (int i = 0; i < 4; ++i)                        \
                _Pragma("unroll") for (int j = 0; j < 4; ++j)                    \
                    acc[i][j] = __builtin_amdgcn_mfma_f32_16x16x32_bf16(af[i], bg[j], acc[i][j], 0, 0, 0); \
        }                                                                        \
    } while (0)

    bf16x8 gA[4], gB[4], gA2[4], gB2[4];
    LOADT(0, gA, gB);
    STORET(gA, gB);   LOADT(1, gA2, gB2); __syncthreads(); COMPUTE(); __syncthreads();
    STORET(gA2, gB2); LOADT(2, gA, gB);   __syncthreads(); COMPUTE(); __syncthreads();
    STORET(gA, gB);   LOADT(3, gA2, gB2); __syncthreads(); COMPUTE(); __syncthreads();
    STORET(gA2, gB2);                     __syncthreads(); COMPUTE();

#undef LOADT
#undef STORET
#undef COMPUTE

    int m_base = mt * 128 + wm * 64;
    int n_base = nt * 128 + wn * 64;
#pragma unroll
    for (int i = 0; i < 4; ++i) {
#pragma unroll
        for (int j = 0; j < 4; ++j) {
            int v = n_base + j * 16 + lr;
            float bias = b_fc[v];
#pragma unroll
            for (int q = 0; q < 4; ++q) {
                int m = m_base + i * 16 + lk * 4 + q;
                out[(size_t)m * VV + v] = acc[i][j][q] + bias;
            }
        }
    }
}

extern "C" void kernel_launch(void* const* d_in, const int* in_sizes, int n_in,
                              void* d_out, int out_size, void* d_ws, size_t ws_size,
                              hipStream_t stream) {
    (void)in_sizes; (void)n_in; (void)out_size; (void)ws_size;
    const float* features   = (const float*)d_in[0];
    const float* embeddings = (const float*)d_in[1];
    const float* W_init     = (const float*)d_in[2];
    const float* b_init     = (const float*)d_in[3];
    const float* W_fc2      = (const float*)d_in[4];
    const float* b_fc2      = (const float*)d_in[5];
    const float* W_ih       = (const float*)d_in[6];
    const float* b_ih       = (const float*)d_in[7];
    const float* W_hh       = (const float*)d_in[8];
    const float* b_hh       = (const float*)d_in[9];
    const float* W_fc       = (const float*)d_in[10];
    const float* b_fc       = (const float*)d_in[11];

    char* ws = (char*)d_ws;
    float* mean_f = (float*)(ws);                              // @0        64 KB
    float* feat   = (float*)(ws + 65536);                      // @64K      32 KB
    float* hbuf0  = (float*)(ws + 98304);                      // @96K      32 KB
    float* gfeat  = (float*)(ws + 131072);                     // @128K     96 KB
    unsigned short* hA = (unsigned short*)(ws + 229376);       // @224K     1.875 MB (ends ~2.1 MB)
    float* gi     = (float*)(ws + 4194304);                    // @4M       11.25 MB
    float* part   = (float*)(ws + 4194304);                    // overlays gi BEFORE gi written (8 MB)
    __hip_bfloat16* wfc = (__hip_bfloat16*)(ws + 4194304);     // overlays gi AFTER gru (16 MB)
    float* outp = (float*)d_out;

    k_mean<<<dim3(16, 32), 256, 0, stream>>>(features, mean_f);
    k_h0<<<32, 256, 0, stream>>>(mean_f, W_init, b_init, hbuf0);
    k_fc2a<<<256, 256, 0, stream>>>(features, W_fc2, part);
    k_fc2b<<<32, 256, 0, stream>>>(part, b_fc2, feat);
    k_gfeat<<<dim3(4, 2), 256, 0, stream>>>(feat, W_ih, b_ih, gfeat);
    k_gi<<<dim3(4, 120, 2), 256, 0, stream>>>(embeddings, gfeat, W_ih, gi);
    k_gru<<<32, 768, 0, stream>>>(hbuf0, gi, W_hh, b_hh, hA);
    k_cvt<<<8000, 256, 0, stream>>>(W_fc, wfc);
    k_logits<<<dim3(250, 30), 256, 0, stream>>>((const __hip_bfloat16*)hA, wfc, b_fc, outp);
}

// Round 7
// 809.107 us; speedup vs baseline: 1.5803x; 1.5803x over previous
//
#include <hip/hip_runtime.h>
#include <hip/hip_bf16.h>

#define BB 32
#define TT 120
#define EE 300
#define HH 256
#define VV 32000
#define CC 512
#define GG 49      // 7*7
#define KIN 556    // E+H
#define CF 25088   // C*49

typedef __attribute__((ext_vector_type(8))) short bf16x8;
typedef __attribute__((ext_vector_type(4))) float f32x4;

// ---- packed-bf16 helpers ----
__device__ __forceinline__ float bpair_lo(unsigned int u) { return __uint_as_float(u << 16); }
__device__ __forceinline__ float bpair_hi(unsigned int u) { return __uint_as_float(u & 0xFFFF0000u); }

__device__ __forceinline__ unsigned int packbf(float a, float b) {
    union { __hip_bfloat16 h; unsigned short u; } ua, ub;
    ua.h = __float2bfloat16(a); ub.h = __float2bfloat16(b);
    return (unsigned int)ua.u | ((unsigned int)ub.u << 16);
}
__device__ __forceinline__ unsigned short f2bu(float x) {
    union { __hip_bfloat16 h; unsigned short u; } v; v.h = __float2bfloat16(x); return v.u;
}

#if defined(__has_builtin)
#  if __has_builtin(__builtin_amdgcn_fdot2_f32_bf16)
#    define USE_DOT2 1
#  endif
#endif
#ifndef USE_DOT2
#  define USE_DOT2 0
#endif

#if USE_DOT2
typedef __bf16 bf2_t __attribute__((ext_vector_type(2)));
__device__ __forceinline__ float dot2bf(unsigned int w, unsigned int h, float c) {
    return __builtin_amdgcn_fdot2_f32_bf16(__builtin_bit_cast(bf2_t, w),
                                           __builtin_bit_cast(bf2_t, h), c, false);
}
#else
__device__ __forceinline__ float dot2bf(unsigned int w, unsigned int h, float c) {
    c = fmaf(bpair_lo(w), bpair_lo(h), c);
    c = fmaf(bpair_hi(w), bpair_hi(h), c);
    return c;
}
#endif

// ---------------- mean: features [B,C,49] -> mean_f [B,C], 512 blocks ----------------
__global__ void __launch_bounds__(256) k_mean(const float* __restrict__ features,
                                              float* __restrict__ mean_f) {
    int q = blockIdx.x;   // c-chunk 0..15 (32 c each)
    int b = blockIdx.y;
    __shared__ float lds[32 * GG];
    const float* src = features + (size_t)b * CF + (size_t)q * 32 * GG;
    for (int i = threadIdx.x; i < 32 * GG; i += 256) lds[i] = src[i];
    __syncthreads();
    if (threadIdx.x < 32) {
        const float* p = &lds[threadIdx.x * GG];
        float s = 0.f;
#pragma unroll
        for (int i = 0; i < GG; ++i) s += p[i];
        mean_f[b * CC + q * 32 + threadIdx.x] = s * (1.0f / 49.0f);
    }
}

// ---------------- h0 = mean_f @ W_init.T + b_init -> [B,H] ----------------
__global__ void k_h0(const float* __restrict__ mean_f, const float* __restrict__ W_init,
                     const float* __restrict__ b_init, float* __restrict__ h0) {
    __shared__ float mf[CC];
    int b = blockIdx.x;
    for (int i = threadIdx.x; i < CC; i += 256) mf[i] = mean_f[b * CC + i];
    __syncthreads();
    int h = threadIdx.x;
    const float* w = W_init + (size_t)h * CC;
    float s = 0.f;
    for (int k = 0; k < CC; k += 4) {
        float4 w4 = *(const float4*)(w + k);
        s += mf[k] * w4.x + mf[k + 1] * w4.y + mf[k + 2] * w4.z + mf[k + 3] * w4.w;
    }
    h0[b * HH + h] = s + b_init[h];
}

// ---------------- fc2 stage A: K-split partial GEMM (round-4 verbatim, VGPR 64) ----------------
__global__ void __launch_bounds__(256) k_fc2a(const float* __restrict__ features,
                                              const float* __restrict__ W_fc2,
                                              float* __restrict__ part) {
    int kc = blockIdx.x;
    __shared__ float xs[98][BB];
    for (int idx = threadIdx.x; idx < 98 * BB; idx += 256) {
        int ii = idx >> 5, b = idx & 31;
        int ig = kc * 98 + ii;
        int c = ig & 511, p = ig >> 9;
        xs[ii][b] = features[(size_t)b * CF + c * GG + p];
    }
    __syncthreads();
    int h = threadIdx.x;
    float acc[BB];
#pragma unroll
    for (int b = 0; b < BB; ++b) acc[b] = 0.f;
    const float* wp = W_fc2 + (size_t)h * CF + kc * 98;
    for (int ii = 0; ii < 98; ii += 2) {
        float2 w2 = *(const float2*)(wp + ii);
        const float4* x0 = (const float4*)&xs[ii][0];
        const float4* x1 = (const float4*)&xs[ii + 1][0];
#pragma unroll
        for (int q = 0; q < 8; ++q) {
            float4 a4 = x0[q], b4 = x1[q];
            acc[4 * q + 0] += w2.x * a4.x + w2.y * b4.x;
            acc[4 * q + 1] += w2.x * a4.y + w2.y * b4.y;
            acc[4 * q + 2] += w2.x * a4.z + w2.y * b4.z;
            acc[4 * q + 3] += w2.x * a4.w + w2.y * b4.w;
        }
    }
    float* pp = part + (size_t)kc * (BB * 256) + h;
#pragma unroll
    for (int b = 0; b < BB; ++b) pp[b * 256] = acc[b];
}

// ---------------- fc2 stage B: reduce partials -> feat [B,H] ----------------
__global__ void k_fc2b(const float* __restrict__ part, const float* __restrict__ b_fc2,
                       float* __restrict__ feat) {
    int b = blockIdx.x;
    int h = threadIdx.x;
    float s = b_fc2[h];
    const float* pp = part + b * 256 + h;
#pragma unroll 8
    for (int kc = 0; kc < 256; ++kc) s += pp[(size_t)kc * (BB * 256)];
    feat[b * HH + h] = s;
}

// ---------------- gfeat[b][g] = feat @ W_ih[:,300:].T + b_ih  (time-invariant part) ----------------
__global__ void __launch_bounds__(256) k_gfeat(const float* __restrict__ feat,
                                               const float* __restrict__ W_ih,
                                               const float* __restrict__ b_ih,
                                               float* __restrict__ gfeat) {
    int ch = blockIdx.x;   // 0..3
    int bh = blockIdx.y;   // 0..1
    __shared__ float xf[16][HH + 1];
    for (int i = threadIdx.x; i < 16 * HH; i += 256) {
        int r = i >> 8, c = i & 255;
        xf[r][c] = feat[(bh * 16 + r) * HH + c];
    }
    __syncthreads();
    int bloc = threadIdx.x & 15;
    int jj   = threadIdx.x >> 4;
    int g0   = ch * 192 + jj;
    float acc[12];
#pragma unroll
    for (int i = 0; i < 12; ++i) acc[i] = 0.f;
    for (int k = 0; k < HH; k += 4) {
        float x0 = xf[bloc][k], x1 = xf[bloc][k + 1], x2 = xf[bloc][k + 2], x3 = xf[bloc][k + 3];
#pragma unroll
        for (int i = 0; i < 12; ++i) {
            float4 w4 = *(const float4*)(W_ih + (size_t)(g0 + i * 16) * KIN + EE + k);
            acc[i] += x0 * w4.x + x1 * w4.y + x2 * w4.z + x3 * w4.w;
        }
    }
    float* outp = gfeat + (size_t)(bh * 16 + bloc) * 768;
#pragma unroll
    for (int i = 0; i < 12; ++i) {
        int g = g0 + i * 16;
        outp[g] = acc[i] + b_ih[g];
    }
}

// ---------------- gi[t,b,g] = emb-part + gfeat ----------------
__global__ void __launch_bounds__(256) k_gi(const float* __restrict__ emb,
                                            const float* __restrict__ gfeat,
                                            const float* __restrict__ W_ih,
                                            float* __restrict__ gi) {
    int ch = blockIdx.x;   // 0..3
    int t  = blockIdx.y;   // 0..119
    int bh = blockIdx.z;   // 0..1
    __shared__ float x[16][EE + 1];   // 19.3 KB
    for (int i = threadIdx.x; i < 16 * EE; i += 256) {
        int r = i / EE, c = i - r * EE;
        x[r][c] = emb[(size_t)(bh * 16 + r) * TT * EE + (size_t)t * EE + c];
    }
    __syncthreads();
    int bloc = threadIdx.x & 15;
    int jj   = threadIdx.x >> 4;
    int g0   = ch * 192 + jj;
    float acc[12];
#pragma unroll
    for (int i = 0; i < 12; ++i) acc[i] = 0.f;
    for (int k = 0; k < EE; k += 4) {
        float x0 = x[bloc][k], x1 = x[bloc][k + 1], x2 = x[bloc][k + 2], x3 = x[bloc][k + 3];
#pragma unroll
        for (int i = 0; i < 12; ++i) {
            float4 w4 = *(const float4*)(W_ih + (size_t)(g0 + i * 16) * KIN + k);
            acc[i] += x0 * w4.x + x1 * w4.y + x2 * w4.z + x3 * w4.w;
        }
    }
    int bg = bh * 16 + bloc;
    float* outp = gi + ((size_t)t * BB + bg) * 768;
    const float* gf = gfeat + (size_t)bg * 768;
#pragma unroll
    for (int i = 0; i < 12; ++i) {
        int g = g0 + i * 16;
        outp[g] = acc[i] + gf[g];
    }
}

// ---------------- persistent GRU: 32 blocks x 768 threads, 2 barriers/step ----------------
__global__ void __launch_bounds__(768, 3) k_gru(const float* __restrict__ h0,
                                                const float* __restrict__ gi,
                                                const float* __restrict__ W_hh,
                                                const float* __restrict__ b_hh,
                                                unsigned short* __restrict__ hA) {
    int b  = blockIdx.x;
    int jp = threadIdx.x;
    int j  = jp & 255;
    int g  = jp >> 8;
    __shared__ unsigned int h_pk[128];          // packed bf16 h pairs
    __shared__ float r_sh[256];
    __shared__ float z_sh[256];
    __shared__ unsigned short hAt[40][256];     // 20 KB chunk of h history

    unsigned int wreg[128];
    const float* wrow = W_hh + (size_t)jp * HH;
#pragma unroll
    for (int kk = 0; kk < 128; ++kk) {
        float2 w2 = *(const float2*)(wrow + 2 * kk);
        wreg[kk] = packbf(w2.x, w2.y);
    }
    float bias  = b_hh[jp];
    float hprev = (g == 2) ? h0[b * HH + j] : 0.f;
    if (jp < 128) {
        float2 hp2 = *(const float2*)(h0 + b * HH + 2 * jp);
        h_pk[jp] = packbf(hp2.x, hp2.y);
    }
    __syncthreads();

    const float* gip = gi + (size_t)b * 768 + jp;    // + t*BB*768 per step
    float gx = gip[0];

    for (int tc = 0; tc < 3; ++tc) {
        for (int tl = 0; tl < 40; ++tl) {
            int t = tc * 40 + tl;
            float a0 = 0.f, a1 = 0.f, a2 = 0.f, a3 = 0.f;
#pragma unroll
            for (int kk = 0; kk < 128; kk += 4) {
                uint4 hq = *(const uint4*)&h_pk[kk];
                a0 = dot2bf(wreg[kk + 0], hq.x, a0);
                a1 = dot2bf(wreg[kk + 1], hq.y, a1);
                a2 = dot2bf(wreg[kk + 2], hq.z, a2);
                a3 = dot2bf(wreg[kk + 3], hq.w, a3);
            }
            float a = (a0 + a1) + (a2 + a3);
            if (g == 0)      r_sh[j] = 1.f / (1.f + __expf(-(gx + a + bias)));
            else if (g == 1) z_sh[j] = 1.f / (1.f + __expf(-(gx + a + bias)));
            __syncthreads();                              // A: r,z visible
            if (g == 2) {
                float n  = tanhf(gx + r_sh[j] * (a + bias));
                float z  = z_sh[j];
                float hn = (1.f - z) * n + z * hprev;
                hprev = hn;
                hAt[tl][j] = f2bu(hn);
                float hnb = __shfl_xor(hn, 1);
                if ((j & 1) == 0) h_pk[j >> 1] = packbf(hn, hnb);
            }
            __syncthreads();                              // B: h_pk ready
            if (t + 1 < TT) gx = gip[(size_t)(t + 1) * (BB * 768)];
        }
        // coalesced flush of 40-step chunk (uint = 2 bf16)
        for (int idx = jp; idx < 40 * 128; idx += 768) {
            int tl = idx >> 7, jh = idx & 127;
            unsigned int v = *(const unsigned int*)&hAt[tl][jh * 2];
            *(unsigned int*)&hA[((size_t)b * TT + tc * 40 + tl) * HH + jh * 2] = v;
        }
        __syncthreads();
    }
}

// ---------------- W_fc f32 -> bf16 ----------------
__global__ void k_cvt(const float* __restrict__ src, __hip_bfloat16* __restrict__ dst) {
    size_t i = ((size_t)blockIdx.x * 256 + threadIdx.x) * 4;
    float4 v = *(const float4*)(src + i);
    __hip_bfloat16 o[4];
    o[0] = __float2bfloat16(v.x);
    o[1] = __float2bfloat16(v.y);
    o[2] = __float2bfloat16(v.z);
    o[3] = __float2bfloat16(v.w);
    *(uint2*)(dst + i) = *(uint2*)o;
}

// ---------------- logits: LDS-staged MFMA GEMM, 128x128 tile, BK=64 ----------------
__global__ void __launch_bounds__(256) k_logits(const __hip_bfloat16* __restrict__ hA,
                                                const __hip_bfloat16* __restrict__ wfc,
                                                const float* __restrict__ b_fc,
                                                float* __restrict__ out) {
    __shared__ short As[128][64];
    __shared__ short Bs[128][64];
    char* AsB = (char*)As;
    char* BsB = (char*)Bs;

    int nt = blockIdx.x;
    int mt = blockIdx.y;
    int tid  = threadIdx.x;
    int wave = tid >> 6, lane = tid & 63;
    int wm = wave >> 1, wn = wave & 1;
    int lr = lane & 15;
    int lk = lane >> 4;

    int rs = tid >> 3;
    int cs = tid & 7;
    const short* Ag = (const short*)hA  + (size_t)mt * 128 * HH + (size_t)rs * HH + cs * 8;
    const short* Bg = (const short*)wfc + (size_t)nt * 128 * HH + (size_t)rs * HH + cs * 8;
    int wswz = (cs ^ (rs & 7)) * 16;
    int wofs[4];
#pragma unroll
    for (int p = 0; p < 4; ++p) wofs[p] = (p * 32 + rs) * 128 + wswz;

    f32x4 acc[4][4] = {};

#define LOADT(kt, GA, GB)                                                        \
    do {                                                                         \
        _Pragma("unroll") for (int p = 0; p < 4; ++p)                            \
            GA[p] = *(const bf16x8*)(Ag + (size_t)p * 32 * HH + (kt) * 64);      \
        _Pragma("unroll") for (int p = 0; p < 4; ++p)                            \
            GB[p] = *(const bf16x8*)(Bg + (size_t)p * 32 * HH + (kt) * 64);      \
    } while (0)

#define STORET(GA, GB)                                                           \
    do {                                                                         \
        _Pragma("unroll") for (int p = 0; p < 4; ++p)                            \
            *(bf16x8*)(AsB + wofs[p]) = GA[p];                                   \
        _Pragma("unroll") for (int p = 0; p < 4; ++p)                            \
            *(bf16x8*)(BsB + wofs[p]) = GB[p];                                   \
    } while (0)

#define COMPUTE()                                                                \
    do {                                                                         \
        _Pragma("unroll") for (int kk = 0; kk < 2; ++kk) {                       \
            bf16x8 af[4], bg[4];                                                 \
            _Pragma("unroll") for (int i = 0; i < 4; ++i) {                      \
                int r = wm * 64 + i * 16 + lr;                                   \
                af[i] = *(const bf16x8*)(AsB + r * 128 + (((kk * 4 + lk) ^ (r & 7)) * 16)); \
            }                                                                    \
            _Pragma("unroll") for (int j = 0; j < 4; ++j) {                      \
                int r = wn * 64 + j * 16 + lr;                                   \
                bg[j] = *(const bf16x8*)(BsB + r * 128 + (((kk * 4 + lk) ^ (r & 7)) * 16)); \
            }                                                                    \
            _Pragma("unroll") for (int i = 0; i < 4; ++i)                        \
                _Pragma("unroll") for (int j = 0; j < 4; ++j)                    \
                    acc[i][j] = __builtin_amdgcn_mfma_f32_16x16x32_bf16(af[i], bg[j], acc[i][j], 0, 0, 0); \
        }                                                                        \
    } while (0)

    bf16x8 gA[4], gB[4], gA2[4], gB2[4];
    LOADT(0, gA, gB);
    STORET(gA, gB);   LOADT(1, gA2, gB2); __syncthreads(); COMPUTE(); __syncthreads();
    STORET(gA2, gB2); LOADT(2, gA, gB);   __syncthreads(); COMPUTE(); __syncthreads();
    STORET(gA, gB);   LOADT(3, gA2, gB2); __syncthreads(); COMPUTE(); __syncthreads();
    STORET(gA2, gB2);                     __syncthreads(); COMPUTE();

#undef LOADT
#undef STORET
#undef COMPUTE

    int m_base = mt * 128 + wm * 64;
    int n_base = nt * 128 + wn * 64;
#pragma unroll
    for (int i = 0; i < 4; ++i) {
#pragma unroll
        for (int j = 0; j < 4; ++j) {
            int v = n_base + j * 16 + lr;
            float bias = b_fc[v];
#pragma unroll
            for (int q = 0; q < 4; ++q) {
                int m = m_base + i * 16 + lk * 4 + q;
                out[(size_t)m * VV + v] = acc[i][j][q] + bias;
            }
        }
    }
}

extern "C" void kernel_launch(void* const* d_in, const int* in_sizes, int n_in,
                              void* d_out, int out_size, void* d_ws, size_t ws_size,
                              hipStream_t stream) {
    (void)in_sizes; (void)n_in; (void)out_size; (void)ws_size;
    const float* features   = (const float*)d_in[0];
    const float* embeddings = (const float*)d_in[1];
    const float* W_init     = (const float*)d_in[2];
    const float* b_init     = (const float*)d_in[3];
    const float* W_fc2      = (const float*)d_in[4];
    const float* b_fc2      = (const float*)d_in[5];
    const float* W_ih       = (const float*)d_in[6];
    const float* b_ih       = (const float*)d_in[7];
    const float* W_hh       = (const float*)d_in[8];
    const float* b_hh       = (const float*)d_in[9];
    const float* W_fc       = (const float*)d_in[10];
    const float* b_fc       = (const float*)d_in[11];

    char* ws = (char*)d_ws;
    float* mean_f = (float*)(ws);                              // @0        64 KB
    float* feat   = (float*)(ws + 65536);                      // @64K      32 KB
    float* hbuf0  = (float*)(ws + 98304);                      // @96K      32 KB
    float* gfeat  = (float*)(ws + 131072);                     // @128K     96 KB
    unsigned short* hA = (unsigned short*)(ws + 229376);       // @224K     1.875 MB
    float* gi     = (float*)(ws + 4194304);                    // @4M       11.25 MB
    float* part   = (float*)(ws + 4194304);                    // overlays gi BEFORE gi written (8 MB)
    __hip_bfloat16* wfc = (__hip_bfloat16*)(ws + 4194304);     // overlays gi AFTER gru (16 MB)
    float* outp = (float*)d_out;

    k_mean<<<dim3(16, 32), 256, 0, stream>>>(features, mean_f);
    k_h0<<<32, 256, 0, stream>>>(mean_f, W_init, b_init, hbuf0);
    k_fc2a<<<256, 256, 0, stream>>>(features, W_fc2, part);
    k_fc2b<<<32, 256, 0, stream>>>(part, b_fc2, feat);
    k_gfeat<<<dim3(4, 2), 256, 0, stream>>>(feat, W_ih, b_ih, gfeat);
    k_gi<<<dim3(4, 120, 2), 256, 0, stream>>>(embeddings, gfeat, W_ih, gi);
    k_gru<<<32, 768, 0, stream>>>(hbuf0, gi, W_hh, b_hh, hA);
    k_cvt<<<8000, 256, 0, stream>>>(W_fc, wfc);
    k_logits<<<dim3(250, 30), 256, 0, stream>>>((const __hip_bfloat16*)hA, wfc, b_fc, outp);
}